// Round 1
// baseline (829.295 us; speedup 1.0000x reference)
//
#include <hip/hip_runtime.h>

// out[b,h,i,j] = mask[b,h,i,j] - |slope(h) * (i - j)|
// B=2, NH=16, L=2048 (powers of two -> index decode by shift/mask).
// slope(h) = 2^{-(h+1)/2} since NH=16 is a power of two.
// Pure streaming op: 512 MiB in + 512 MiB out => HBM-bound, float4 vectorized.

static constexpr int LOG2_L  = 11;   // L = 2048
static constexpr int LOG2_LL = 22;   // L*L = 2^22
static constexpr int NH_MASK = 15;   // NH = 16
static constexpr int L_MASK  = 2047;

__global__ __launch_bounds__(256) void alibi_kernel(
    const float4* __restrict__ mask4, float4* __restrict__ out4, unsigned int n4)
{
    unsigned int idx = blockIdx.x * 256u + threadIdx.x;
    if (idx >= n4) return;

    // flat element index of the first of this thread's 4 elements
    unsigned int e  = idx << 2;
    int j  = (int)(e & L_MASK);                 // fast dim (4 consecutive j)
    int i  = (int)((e >> LOG2_L) & L_MASK);
    int nh = (int)((e >> LOG2_LL) & NH_MASK);

    float slope = exp2f(-0.5f * (float)(nh + 1));
    float rel   = (float)(i - j);

    float4 m = mask4[idx];
    float4 o;
    o.x = m.x - fabsf(slope * rel);
    o.y = m.y - fabsf(slope * (rel - 1.0f));
    o.z = m.z - fabsf(slope * (rel - 2.0f));
    o.w = m.w - fabsf(slope * (rel - 3.0f));
    out4[idx] = o;
}

extern "C" void kernel_launch(void* const* d_in, const int* in_sizes, int n_in,
                              void* d_out, int out_size, void* d_ws, size_t ws_size,
                              hipStream_t stream) {
    const float4* mask4 = (const float4*)d_in[0];
    float4* out4 = (float4*)d_out;
    unsigned int n4 = (unsigned int)(out_size >> 2);   // 33,554,432 float4s
    unsigned int blocks = (n4 + 255u) / 256u;
    alibi_kernel<<<blocks, 256, 0, stream>>>(mask4, out4, n4);
}